// Round 3
// baseline (4882.716 us; speedup 1.0000x reference)
//
#include <hip/hip_runtime.h>

typedef unsigned short u16;
typedef unsigned int uint;

using f32x4 = __attribute__((ext_vector_type(4))) float;
using bf16x8 = __attribute__((ext_vector_type(8))) __bf16;

static __device__ __forceinline__ bf16x8 as_bf16x8(uint4 u) {
    union { uint4 a; bf16x8 b; } c; c.a = u; return c.b;
}
static __device__ __forceinline__ float bf2f(u16 h) {
    union { uint u; float f; } c; c.u = ((uint)h) << 16; return c.f;
}
static __device__ __forceinline__ u16 f2bf(float f) {
    union { float f; uint u; } c; c.f = f;
    uint u = c.u;
    return (u16)((u + 0x7fffu + ((u >> 16) & 1u)) >> 16);
}
static __device__ __forceinline__ float fast_sigmoid(float x) {
    x = fminf(30.f, fmaxf(-30.f, x));
    return __builtin_amdgcn_rcpf(1.0f + __builtin_amdgcn_exp2f(x * -1.44269504f));
}
static __device__ __forceinline__ float fast_tanh(float x) {
    x = fminf(15.f, fmaxf(-15.f, x));
    return 1.0f - 2.0f * __builtin_amdgcn_rcpf(1.0f + __builtin_amdgcn_exp2f(x * 2.88539008f));
}

// dtype detector: for bf16 data the low half of each 32b word has exp field
// < 0x80 (values << 2); for fp32 data bits[14:7] are random mantissa bits
// (>= 0x80 with p~0.5). Deterministic per buffer -> graph-capture safe.
static __device__ __forceinline__ int detect_fp32(const uint* w, int nwords) {
    int hits = 0;
    for (int i = 0; i < nwords; ++i) { uint e = (w[i] >> 7) & 0xffu; hits += (e >= 0x80u); }
    return hits > (nwords >> 3);
}
static __device__ __forceinline__ u16 load_bf(const void* p, int i, int fp32) {
    return fp32 ? f2bf(((const float*)p)[i]) : ((const u16*)p)[i];
}

// Pack weights [K,256] x 4 gates -> Wp[n][k], n = u*4 + g (gate-minor), k padded.
__global__ void pack_w(const void* wf, const void* wi, const void* wc, const void* wo,
                       const void* bbf, const void* bbi, const void* bbc, const void* bbo,
                       u16* __restrict__ wp, u16* __restrict__ bp, int K, int Kpad) {
    __shared__ int sfp;
    if (threadIdx.x == 0) sfp = detect_fp32((const uint*)wf, 256);
    __syncthreads();
    const int fp32 = sfp;
    int n = blockIdx.x;            // 0..1023
    int u = n >> 2, g = n & 3;
    const void* w = (g == 0) ? wf : (g == 1) ? wi : (g == 2) ? wc : wo;
    const void* b = (g == 0) ? bbf : (g == 1) ? bbi : (g == 2) ? bbc : bbo;
    for (int k = threadIdx.x; k < Kpad; k += blockDim.x)
        wp[n * Kpad + k] = (k < K) ? load_bf(w, k * 256 + u, fp32) : (u16)0;
    if (threadIdx.x == 0) bp[n] = load_bf(b, u, fp32);
}

// Pack embedding table + w_out/b_out to bf16 in workspace.
__global__ void pack_misc(const void* emb, const void* w_out, const void* b_out,
                          u16* __restrict__ embp, u16* __restrict__ wob,
                          u16* __restrict__ bob) {
    __shared__ int sfp;
    if (threadIdx.x == 0) sfp = detect_fp32((const uint*)emb, 256);
    __syncthreads();
    const int fp32 = sfp;
    int stride = gridDim.x * blockDim.x;
    for (int i = blockIdx.x * blockDim.x + threadIdx.x; i < 1000000; i += stride)
        embp[i] = load_bf(emb, i, fp32);
    if (blockIdx.x == 0) {
        __shared__ int sfp2;
        if (threadIdx.x == 0) sfp2 = detect_fp32((const uint*)w_out, 128);
        __syncthreads();
        if (threadIdx.x < 256) wob[threadIdx.x] = load_bf(w_out, threadIdx.x, sfp2);
        if (threadIdx.x == 0) bob[0] = load_bf(b_out, 0, sfp2);
    }
}

// K-loop: acc[nt] += HX[16,K] x Wp[K, 16 cols at w*128+nt*16]
template <int KSTEPS, int KPAD, int HXS>
static __device__ __forceinline__ void kloop(const u16* __restrict__ wp, const u16* hx,
                                             int w, int c16, int q, f32x4 acc[8]) {
    const u16* aptr = hx + c16 * HXS + q * 8;
    const u16* bbase = wp + (w * 128 + c16) * KPAD + q * 8;
    uint4 bb[2][8];
#pragma unroll
    for (int nt = 0; nt < 8; ++nt)
        bb[0][nt] = *(const uint4*)(bbase + nt * 16 * KPAD);
#pragma unroll
    for (int ks = 0; ks < KSTEPS; ++ks) {
        int cur = ks & 1;
        if (ks + 1 < KSTEPS) {
#pragma unroll
            for (int nt = 0; nt < 8; ++nt)
                bb[cur ^ 1][nt] = *(const uint4*)(bbase + (ks + 1) * 32 + nt * 16 * KPAD);
        }
        bf16x8 a = as_bf16x8(*(const uint4*)(aptr + ks * 32));
#pragma unroll
        for (int nt = 0; nt < 8; ++nt)
            acc[nt] = __builtin_amdgcn_mfma_f32_16x16x32_bf16(a, as_bf16x8(bb[cur][nt]), acc[nt], 0, 0, 0);
    }
}

#define HX1S 392   // 384 K-cols + 8 pad
#define HX2S 520   // 512 K-cols + 8 pad
#define SCRS 132   // 128 gate-cols + 4 pad

__global__ void __launch_bounds__(512, 2)
lstm_kernel(const int* __restrict__ tokens, const u16* __restrict__ embp,
            const u16* __restrict__ wp1, const u16* __restrict__ b1p,
            const u16* __restrict__ wp2, const u16* __restrict__ b2p,
            const u16* __restrict__ wob, const u16* __restrict__ bob,
            float* __restrict__ out) {
    __shared__ __align__(16) u16 hx1[16 * HX1S];        // [r][ h1(256) | x(100) | 0-pad ]
    __shared__ __align__(16) u16 hx2[16 * HX2S];        // [r][ h2(256) | h1(256) ]
    __shared__ __align__(16) u16 scr[8 * 16 * SCRS];    // per-wave Z scratch

    const int tid = threadIdx.x;
    const int lane = tid & 63;
    const int w = tid >> 6;          // wave 0..7 -> gate-cols [128w, 128w+128)
    const int c16 = lane & 15;
    const int q = lane >> 4;
    const int row0 = blockIdx.x * 16;

    const int ul = lane & 31;        // local unit
    const int rh = lane >> 5;        // row half
    const int u = w * 32 + ul;       // global unit

    {
        uint* p1 = (uint*)hx1;
        for (int i = tid; i < 16 * HX1S / 2; i += 512) p1[i] = 0;
        uint* p2 = (uint*)hx2;
        for (int i = tid; i < 16 * HX2S / 2; i += 512) p2[i] = 0;
    }
    float c1s[8], c2s[8];
#pragma unroll
    for (int j = 0; j < 8; ++j) { c1s[j] = 0.f; c2s[j] = 0.f; }

    // gather x(t=0)
    {
        int r = tid >> 5, s32 = tid & 31;
        if (s32 < 25) {
            int tok = tokens[(row0 + r) * 80 + 0];
            ushort4 v = *(const ushort4*)(embp + tok * 100 + s32 * 4);
            *(ushort4*)(hx1 + r * HX1S + 256 + s32 * 4) = v;
        }
    }
    ushort4 bw1 = *(const ushort4*)(b1p + u * 4);
    ushort4 bw2 = *(const ushort4*)(b2p + u * 4);
    const float b1f0 = bf2f(bw1.x), b1f1 = bf2f(bw1.y), b1f2 = bf2f(bw1.z), b1f3 = bf2f(bw1.w);
    const float b2f0 = bf2f(bw2.x), b2f1 = bf2f(bw2.y), b2f2 = bf2f(bw2.z), b2f3 = bf2f(bw2.w);

    __syncthreads();

    u16* sw = scr + w * 16 * SCRS;

#pragma unroll 1
    for (int t = 0; t < 80; ++t) {
        // ---------- Layer 1 GEMM ----------
        f32x4 acc[8];
#pragma unroll
        for (int nt = 0; nt < 8; ++nt) acc[nt] = (f32x4){0.f, 0.f, 0.f, 0.f};
        kloop<12, 384, HX1S>(wp1, hx1, w, c16, q, acc);
#pragma unroll
        for (int nt = 0; nt < 8; ++nt) {
            int nl = nt * 16 + c16;
#pragma unroll
            for (int j = 0; j < 4; ++j)
                sw[(q * 4 + j) * SCRS + nl] = f2bf(acc[nt][j]);
        }
        __syncthreads();  // B1

        // ---------- gates 1 (+ x(t+1) prefetch) ----------
        ushort4 xv;
        int xr = tid >> 5, xs = tid & 31;
        bool xact = (xs < 25) && (t < 79);
        int tok = 0;
        if (xact) tok = tokens[(row0 + xr) * 80 + t + 1];
        if (xact) xv = *(const ushort4*)(embp + tok * 100 + xs * 4);
#pragma unroll
        for (int j = 0; j < 8; ++j) {
            int r = rh * 8 + j;
            ushort4 zz = *(const ushort4*)(sw + r * SCRS + ul * 4);
            float gf = fast_sigmoid(bf2f(zz.x) + b1f0);
            float gi = fast_sigmoid(bf2f(zz.y) + b1f1);
            float gc = fast_tanh(bf2f(zz.z) + b1f2);
            float go = fast_sigmoid(bf2f(zz.w) + b1f3);
            float cn = gf * c1s[j] + gi * gc;
            c1s[j] = cn;
            u16 hb = f2bf(go * fast_tanh(cn));
            hx1[r * HX1S + u] = hb;
            hx2[r * HX2S + 256 + u] = hb;
        }
        if (xact) *(ushort4*)(hx1 + xr * HX1S + 256 + xs * 4) = xv;
        __syncthreads();  // B2

        // ---------- Layer 2 GEMM ----------
        f32x4 acc2[8];
#pragma unroll
        for (int nt = 0; nt < 8; ++nt) acc2[nt] = (f32x4){0.f, 0.f, 0.f, 0.f};
        kloop<16, 512, HX2S>(wp2, hx2, w, c16, q, acc2);
#pragma unroll
        for (int nt = 0; nt < 8; ++nt) {
            int nl = nt * 16 + c16;
#pragma unroll
            for (int j = 0; j < 4; ++j)
                sw[(q * 4 + j) * SCRS + nl] = f2bf(acc2[nt][j]);
        }
        __syncthreads();  // B3

        // ---------- gates 2 ----------
#pragma unroll
        for (int j = 0; j < 8; ++j) {
            int r = rh * 8 + j;
            ushort4 zz = *(const ushort4*)(sw + r * SCRS + ul * 4);
            float gf = fast_sigmoid(bf2f(zz.x) + b2f0);
            float gi = fast_sigmoid(bf2f(zz.y) + b2f1);
            float gc = fast_tanh(bf2f(zz.z) + b2f2);
            float go = fast_sigmoid(bf2f(zz.w) + b2f3);
            float cn = gf * c2s[j] + gi * gc;
            c2s[j] = cn;
            hx2[r * HX2S + u] = f2bf(go * fast_tanh(cn));
        }
    }
    __syncthreads();

    // ---------- output: sigmoid(h2 @ w_out + b_out), fp32 store ----------
    {
        int r = tid >> 5, s = tid & 31;
        uint4 hv = *(const uint4*)(hx2 + r * HX2S + s * 8);
        uint4 wv = *(const uint4*)(wob + s * 8);
        const u16* hp = (const u16*)&hv;
        const u16* wp = (const u16*)&wv;
        float dot = 0.f;
#pragma unroll
        for (int i = 0; i < 8; ++i) dot += bf2f(hp[i]) * bf2f(wp[i]);
        float* psum = (float*)scr;
        psum[r * 32 + s] = dot;
        __syncthreads();
        if (tid < 16) {
            float ssum = 0.f;
            for (int i = 0; i < 32; ++i) ssum += psum[tid * 32 + i];
            out[row0 + tid] = fast_sigmoid(ssum + bf2f(bob[0]));
        }
    }
}

extern "C" void kernel_launch(void* const* d_in, const int* in_sizes, int n_in,
                              void* d_out, int out_size, void* d_ws, size_t ws_size,
                              hipStream_t stream) {
    const int* tokens = (const int*)d_in[0];
    const void* emb = d_in[1];
    const void* wf1 = d_in[2];  const void* bf1_ = d_in[3];
    const void* wi1 = d_in[4];  const void* bi1_ = d_in[5];
    const void* wc1 = d_in[6];  const void* bc1_ = d_in[7];
    const void* wo1 = d_in[8];  const void* bo1_ = d_in[9];
    const void* wf2 = d_in[10]; const void* bf2_ = d_in[11];
    const void* wi2 = d_in[12]; const void* bi2_ = d_in[13];
    const void* wc2 = d_in[14]; const void* bc2_ = d_in[15];
    const void* wo2 = d_in[16]; const void* bo2_ = d_in[17];
    const void* w_out = d_in[18];
    const void* b_out = d_in[19];

    u16* wp1 = (u16*)d_ws;                 // 1024 x 384
    u16* wp2 = wp1 + 1024 * 384;           // 1024 x 512
    u16* b1p = wp2 + 1024 * 512;           // 1024
    u16* b2p = b1p + 1024;                 // 1024
    u16* wob = b2p + 1024;                 // 256
    u16* bob = wob + 256;                  // 8 (pad)
    u16* embp = bob + 8;                   // 1,000,000 (16B-aligned)

    pack_w<<<dim3(1024), dim3(64), 0, stream>>>(wf1, wi1, wc1, wo1, bf1_, bi1_, bc1_, bo1_,
                                                wp1, b1p, 356, 384);
    pack_w<<<dim3(1024), dim3(64), 0, stream>>>(wf2, wi2, wc2, wo2, bf2_, bi2_, bc2_, bo2_,
                                                wp2, b2p, 512, 512);
    pack_misc<<<dim3(512), dim3(256), 0, stream>>>(emb, w_out, b_out, embp, wob, bob);
    lstm_kernel<<<dim3(64), dim3(512), 0, stream>>>(tokens, embp, wp1, b1p, wp2, b2p,
                                                    wob, bob, (float*)d_out);
}

// Round 4
// 3702.917 us; speedup vs baseline: 1.3186x; 1.3186x over previous
//
#include <hip/hip_runtime.h>

typedef unsigned short u16;
typedef unsigned int uint;

using f32x4 = __attribute__((ext_vector_type(4))) float;
using bf16x8 = __attribute__((ext_vector_type(8))) __bf16;

static __device__ __forceinline__ bf16x8 as_bf16x8(uint4 u) {
    union { uint4 a; bf16x8 b; } c; c.a = u; return c.b;
}
static __device__ __forceinline__ float bf2f(u16 h) {
    union { uint u; float f; } c; c.u = ((uint)h) << 16; return c.f;
}
static __device__ __forceinline__ u16 f2bf(float f) {
    union { float f; uint u; } c; c.f = f;
    uint u = c.u;
    return (u16)((u + 0x7fffu + ((u >> 16) & 1u)) >> 16);
}
static __device__ __forceinline__ float fast_sigmoid(float x) {
    x = fminf(30.f, fmaxf(-30.f, x));
    return __builtin_amdgcn_rcpf(1.0f + __builtin_amdgcn_exp2f(x * -1.44269504f));
}
static __device__ __forceinline__ float fast_tanh(float x) {
    x = fminf(15.f, fmaxf(-15.f, x));
    return 1.0f - 2.0f * __builtin_amdgcn_rcpf(1.0f + __builtin_amdgcn_exp2f(x * 2.88539008f));
}

// dtype detector (fp32 vs bf16 buffers) — deterministic, graph-capture safe.
static __device__ __forceinline__ int detect_fp32(const uint* w, int nwords) {
    int hits = 0;
    for (int i = 0; i < nwords; ++i) { uint e = (w[i] >> 7) & 0xffu; hits += (e >= 0x80u); }
    return hits > (nwords >> 3);
}
static __device__ __forceinline__ u16 load_bf(const void* p, int i, int fp32) {
    return fp32 ? f2bf(((const float*)p)[i]) : ((const u16*)p)[i];
}

// Fragment-ordered weight pack:
//   wp[((w*KSTEPS + ks)*4 + nt)*512 + lane*8 + j]
//   n = w*64 + nt*16 + (lane&15) = 4*unit + gate;  k = ks*32 + (lane>>4)*8 + j
// -> every B-fragment load in the main loop is base + lane*16B (coalesced 1KB).
// grid: 16*KSTEPS blocks x 256 threads.
__global__ void pack_w(const void* wf, const void* wi, const void* wc, const void* wo,
                       const void* bbf, const void* bbi, const void* bbc, const void* bbo,
                       u16* __restrict__ wp, u16* __restrict__ bp, int K, int KSTEPS) {
    __shared__ int sfp;
    if (threadIdx.x == 0) sfp = detect_fp32((const uint*)wf, 256);
    __syncthreads();
    const int fp32 = sfp;
    int w = blockIdx.x / KSTEPS, ks = blockIdx.x % KSTEPS;
    int nt = threadIdx.x >> 6, lane = threadIdx.x & 63;
    int c16 = lane & 15, q = lane >> 4;
    int n = w * 64 + nt * 16 + c16;
    int u = n >> 2, g = n & 3;
    const void* W = (g == 0) ? wf : (g == 1) ? wi : (g == 2) ? wc : wo;
    union { u16 v[8]; uint4 u4; } tmp;
#pragma unroll
    for (int j = 0; j < 8; ++j) {
        int k = ks * 32 + q * 8 + j;
        tmp.v[j] = (k < K) ? load_bf(W, k * 256 + u, fp32) : (u16)0;
    }
    *(uint4*)(wp + ((w * KSTEPS + ks) * 4 + nt) * 512 + lane * 8) = tmp.u4;
    if (ks == 0 && threadIdx.x < 64) {
        int n2 = w * 64 + threadIdx.x;
        int g2 = n2 & 3;
        const void* B = (g2 == 0) ? bbf : (g2 == 1) ? bbi : (g2 == 2) ? bbc : bbo;
        bp[n2] = load_bf(B, n2 >> 2, fp32);
    }
}

// Pack embedding table + w_out/b_out to bf16 in workspace.
__global__ void pack_misc(const void* emb, const void* w_out, const void* b_out,
                          u16* __restrict__ embp, u16* __restrict__ wob,
                          u16* __restrict__ bob) {
    __shared__ int sfp;
    if (threadIdx.x == 0) sfp = detect_fp32((const uint*)emb, 256);
    __syncthreads();
    const int fp32 = sfp;
    int stride = gridDim.x * blockDim.x;
    for (int i = blockIdx.x * blockDim.x + threadIdx.x; i < 1000000; i += stride)
        embp[i] = load_bf(emb, i, fp32);
    if (blockIdx.x == 0) {
        __shared__ int sfp2;
        if (threadIdx.x == 0) sfp2 = detect_fp32((const uint*)w_out, 128);
        __syncthreads();
        if (threadIdx.x < 256) wob[threadIdx.x] = load_bf(w_out, threadIdx.x, sfp2);
        if (threadIdx.x == 0) bob[0] = load_bf(b_out, 0, sfp2);
    }
}

// K-loop: acc[nt] += HX[16,K] x W[K, 16 cols], weights in fragment order.
template <int KSTEPS, int HXS>
static __device__ __forceinline__ void kloop(const u16* __restrict__ wslab, const u16* hx,
                                             int lane, f32x4 acc[4]) {
    int c16 = lane & 15, q = lane >> 4;
    const u16* aptr = hx + c16 * HXS + q * 8;
    const u16* bptr = wslab + lane * 8;
    uint4 bb[2][4];
#pragma unroll
    for (int nt = 0; nt < 4; ++nt) bb[0][nt] = *(const uint4*)(bptr + nt * 512);
#pragma unroll
    for (int ks = 0; ks < KSTEPS; ++ks) {
        int cur = ks & 1;
        if (ks + 1 < KSTEPS) {
#pragma unroll
            for (int nt = 0; nt < 4; ++nt)
                bb[cur ^ 1][nt] = *(const uint4*)(bptr + ((ks + 1) * 4 + nt) * 512);
        }
        bf16x8 a = as_bf16x8(*(const uint4*)(aptr + ks * 32));
#pragma unroll
        for (int nt = 0; nt < 4; ++nt)
            acc[nt] = __builtin_amdgcn_mfma_f32_16x16x32_bf16(a, as_bf16x8(bb[cur][nt]), acc[nt], 0, 0, 0);
    }
}

#define HX1S 392   // 384 K-cols + 8 pad
#define HX2S 520   // 512 K-cols + 8 pad
#define SCRS 68    // 64 gate-cols + 4 pad

__global__ void __launch_bounds__(1024, 1)
lstm_kernel(const int* __restrict__ tokens, const u16* __restrict__ embp,
            const u16* __restrict__ wp1, const u16* __restrict__ b1p,
            const u16* __restrict__ wp2, const u16* __restrict__ b2p,
            const u16* __restrict__ wob, const u16* __restrict__ bob,
            float* __restrict__ out) {
    __shared__ __align__(16) u16 hx1[16 * HX1S];        // 12544 B [r][ h1 | x | 0-pad ]
    __shared__ __align__(16) u16 hx2[16 * HX2S];        // 16640 B [r][ h2 | h1 ]
    __shared__ __align__(16) u16 scr[16 * 16 * SCRS];   // 34816 B per-wave Z scratch

    const int tid = threadIdx.x;
    const int lane = tid & 63;
    const int w = tid >> 6;          // wave 0..15 -> gate-cols [64w, 64w+64)
    const int c16 = lane & 15;
    const int q = lane >> 4;
    const int row0 = blockIdx.x * 16;

    const int ul = lane & 15;        // unit-local for gates
    const int U = w * 16 + ul;       // global unit 0..255

    {
        uint* p1 = (uint*)hx1;
        for (int i = tid; i < 16 * HX1S / 2; i += 1024) p1[i] = 0;
        uint* p2 = (uint*)hx2;
        for (int i = tid; i < 16 * HX2S / 2; i += 1024) p2[i] = 0;
    }
    float c1s[4], c2s[4];
#pragma unroll
    for (int j = 0; j < 4; ++j) { c1s[j] = 0.f; c2s[j] = 0.f; }

    // gather x(t=0)
    if (tid < 512) {
        int r = tid >> 5, s32 = tid & 31;
        if (s32 < 25) {
            int tok = tokens[(row0 + r) * 80 + 0];
            ushort4 v = *(const ushort4*)(embp + tok * 100 + s32 * 4);
            *(ushort4*)(hx1 + r * HX1S + 256 + s32 * 4) = v;
        }
    }
    ushort4 bw1 = *(const ushort4*)(b1p + U * 4);
    ushort4 bw2 = *(const ushort4*)(b2p + U * 4);
    const float b1f0 = bf2f(bw1.x), b1f1 = bf2f(bw1.y), b1f2 = bf2f(bw1.z), b1f3 = bf2f(bw1.w);
    const float b2f0 = bf2f(bw2.x), b2f1 = bf2f(bw2.y), b2f2 = bf2f(bw2.z), b2f3 = bf2f(bw2.w);

    __syncthreads();

    u16* sw = scr + w * 16 * SCRS;
    const u16* w1slab = wp1 + w * (12 * 4 * 512);
    const u16* w2slab = wp2 + w * (16 * 4 * 512);

#pragma unroll 1
    for (int t = 0; t < 80; ++t) {
        // ---------- Layer 1 GEMM ----------
        f32x4 acc[4];
#pragma unroll
        for (int nt = 0; nt < 4; ++nt) acc[nt] = (f32x4){0.f, 0.f, 0.f, 0.f};
        kloop<12, HX1S>(w1slab, hx1, lane, acc);
#pragma unroll
        for (int nt = 0; nt < 4; ++nt)
#pragma unroll
            for (int j = 0; j < 4; ++j)
                sw[(q * 4 + j) * SCRS + nt * 16 + c16] = f2bf(acc[nt][j]);
        __syncthreads();  // B1

        // ---------- gates 1 (+ x(t+1) prefetch) ----------
        ushort4 xv;
        int xr = tid >> 5, xs = tid & 31;
        bool xact = (tid < 512) && (xs < 25) && (t < 79);
        if (xact) {
            int tok = tokens[(row0 + xr) * 80 + t + 1];
            xv = *(const ushort4*)(embp + tok * 100 + xs * 4);
        }
#pragma unroll
        for (int j = 0; j < 4; ++j) {
            int r = q * 4 + j;
            ushort4 zz = *(const ushort4*)(sw + r * SCRS + ul * 4);
            float gf = fast_sigmoid(bf2f(zz.x) + b1f0);
            float gi = fast_sigmoid(bf2f(zz.y) + b1f1);
            float gc = fast_tanh(bf2f(zz.z) + b1f2);
            float go = fast_sigmoid(bf2f(zz.w) + b1f3);
            float cn = gf * c1s[j] + gi * gc;
            c1s[j] = cn;
            u16 hb = f2bf(go * fast_tanh(cn));
            hx1[r * HX1S + U] = hb;
            hx2[r * HX2S + 256 + U] = hb;
        }
        if (xact) *(ushort4*)(hx1 + xr * HX1S + 256 + xs * 4) = xv;
        __syncthreads();  // B2

        // ---------- Layer 2 GEMM ----------
        f32x4 acc2[4];
#pragma unroll
        for (int nt = 0; nt < 4; ++nt) acc2[nt] = (f32x4){0.f, 0.f, 0.f, 0.f};
        kloop<16, HX2S>(w2slab, hx2, lane, acc2);
#pragma unroll
        for (int nt = 0; nt < 4; ++nt)
#pragma unroll
            for (int j = 0; j < 4; ++j)
                sw[(q * 4 + j) * SCRS + nt * 16 + c16] = f2bf(acc2[nt][j]);
        __syncthreads();  // B3

        // ---------- gates 2 ----------
#pragma unroll
        for (int j = 0; j < 4; ++j) {
            int r = q * 4 + j;
            ushort4 zz = *(const ushort4*)(sw + r * SCRS + ul * 4);
            float gf = fast_sigmoid(bf2f(zz.x) + b2f0);
            float gi = fast_sigmoid(bf2f(zz.y) + b2f1);
            float gc = fast_tanh(bf2f(zz.z) + b2f2);
            float go = fast_sigmoid(bf2f(zz.w) + b2f3);
            float cn = gf * c2s[j] + gi * gc;
            c2s[j] = cn;
            hx2[r * HX2S + U] = f2bf(go * fast_tanh(cn));
        }
        // scr is wave-private; hx hazards ordered by B1/B2 of next iteration.
    }
    __syncthreads();

    // ---------- output: sigmoid(h2 @ w_out + b_out), fp32 store ----------
    if (tid < 512) {
        int r = tid >> 5, s = tid & 31;
        uint4 hv = *(const uint4*)(hx2 + r * HX2S + s * 8);
        uint4 wv = *(const uint4*)(wob + s * 8);
        const u16* hp = (const u16*)&hv;
        const u16* wp = (const u16*)&wv;
        float dot = 0.f;
#pragma unroll
        for (int i = 0; i < 8; ++i) dot += bf2f(hp[i]) * bf2f(wp[i]);
        float* psum = (float*)scr;
        psum[r * 32 + s] = dot;
    }
    __syncthreads();
    if (tid < 16) {
        float* psum = (float*)scr;
        float ssum = 0.f;
        for (int i = 0; i < 32; ++i) ssum += psum[tid * 32 + i];
        out[row0 + tid] = fast_sigmoid(ssum + bf2f(bob[0]));
    }
}

extern "C" void kernel_launch(void* const* d_in, const int* in_sizes, int n_in,
                              void* d_out, int out_size, void* d_ws, size_t ws_size,
                              hipStream_t stream) {
    const int* tokens = (const int*)d_in[0];
    const void* emb = d_in[1];
    const void* wf1 = d_in[2];  const void* bf1_ = d_in[3];
    const void* wi1 = d_in[4];  const void* bi1_ = d_in[5];
    const void* wc1 = d_in[6];  const void* bc1_ = d_in[7];
    const void* wo1 = d_in[8];  const void* bo1_ = d_in[9];
    const void* wf2 = d_in[10]; const void* bf2_ = d_in[11];
    const void* wi2 = d_in[12]; const void* bi2_ = d_in[13];
    const void* wc2 = d_in[14]; const void* bc2_ = d_in[15];
    const void* wo2 = d_in[16]; const void* bo2_ = d_in[17];
    const void* w_out = d_in[18];
    const void* b_out = d_in[19];

    u16* wp1 = (u16*)d_ws;                 // 16*12*4*512 = 393216
    u16* wp2 = wp1 + 16 * 12 * 4 * 512;    // 16*16*4*512 = 524288
    u16* b1p = wp2 + 16 * 16 * 4 * 512;    // 1024
    u16* b2p = b1p + 1024;                 // 1024
    u16* wob = b2p + 1024;                 // 256
    u16* bob = wob + 256;                  // 8 (pad)
    u16* embp = bob + 8;                   // 1,000,000

    pack_w<<<dim3(16 * 12), dim3(256), 0, stream>>>(wf1, wi1, wc1, wo1, bf1_, bi1_, bc1_, bo1_,
                                                    wp1, b1p, 356, 12);
    pack_w<<<dim3(16 * 16), dim3(256), 0, stream>>>(wf2, wi2, wc2, wo2, bf2_, bi2_, bc2_, bo2_,
                                                    wp2, b2p, 512, 16);
    pack_misc<<<dim3(512), dim3(256), 0, stream>>>(emb, w_out, b_out, embp, wob, bob);
    lstm_kernel<<<dim3(64), dim3(1024), 0, stream>>>(tokens, embp, wp1, b1p, wp2, b2p,
                                                     wob, bob, (float*)d_out);
}